// Round 2
// baseline (112.755 us; speedup 1.0000x reference)
//
#include <hip/hip_runtime.h>
#include <hip/hip_bf16.h>

#define HH 64
#define TT 128
#define BT 16

typedef __attribute__((ext_vector_type(8))) short bf16x8;
typedef __attribute__((ext_vector_type(4))) float f32x4;

__device__ __forceinline__ unsigned short f2bf(float f) {
  union { float f; unsigned u; } v; v.f = f;
  return (unsigned short)((v.u + 0x7FFFu + ((v.u >> 16) & 1u)) >> 16);
}
__device__ __forceinline__ float rcp_(float x) { return __builtin_amdgcn_rcpf(x); }
__device__ __forceinline__ float exp2_(float x) { return __builtin_amdgcn_exp2f(x); }

#define L2E 1.44269504f
#define L2E2 2.88539008f

__device__ __forceinline__ float red32(float v) {
#pragma unroll
  for (int s = 16; s; s >>= 1) v += __shfl_xor(v, s, 32);
  return v;
}

// ---------- kernel 1: embed fp32 -> bf16 ----------
__global__ void convert_embed(const float* __restrict__ src,
                              unsigned short* __restrict__ dst, int n) {
  int base = (blockIdx.x * 256 + threadIdx.x) * 4;
  if (base + 4 <= n) {
    float4 v = *(const float4*)(src + base);
    ushort4 r;
    r.x = f2bf(v.x); r.y = f2bf(v.y); r.z = f2bf(v.z); r.w = f2bf(v.w);
    *(ushort4*)(dst + base) = r;
  } else {
    for (int k = base; k < n; k++) dst[k] = f2bf(src[k]);
  }
}

#define MFMA(acc, a, b) acc = __builtin_amdgcn_mfma_f32_16x16x32_bf16(a, b, acc, 0, 0, 0)

// ---------- kernel 2: fused LSTM (8 waves, gate-split pairing) + head ----------
__global__ __launch_bounds__(512, 1) void lstm_k(
    const int* __restrict__ inst, const unsigned short* __restrict__ ebf,
    const float* __restrict__ Wih, const float* __restrict__ Whh,
    const float* __restrict__ bih, const float* __restrict__ bhh,
    const float* __restrict__ canvas,
    const float* __restrict__ Wc, const float* __restrict__ bc,
    const float* __restrict__ Ws, const float* __restrict__ bs,
    const float* __restrict__ Wo, const float* __restrict__ bo,
    const float* __restrict__ Wr1, const float* __restrict__ br1,
    const float* __restrict__ Wr2, const float* __restrict__ br2,
    float* __restrict__ out, int B)
{
  __shared__ int tokT[TT * BT];                 // [t][b_local]
  __shared__ unsigned short hsh[2 * BT * HH];   // double-buffered h, bf16, XOR-swizzled
  __shared__ float a_s[16][66];                 // i*tanh(g) exchange; h(f32) at the end
  __shared__ float Wr1_s[32 * 69];

  const int tid  = threadIdx.x;
  const int lane = tid & 63;
  const int w    = tid >> 6;       // 0..7
  const int wid  = w & 3;
  const int hi   = w >> 2;         // 0: (i,g) wave, 1: (f,o) wave
  const int fr   = lane & 15;
  const int fg   = lane >> 4;
  const int b0   = blockIdx.x * BT;
  const int jcol = wid * 16 + fr;  // hidden/cell column this lane touches
  const int n0   = hi * 64 + jcol; // gate col of tile0 (i or f)
  const int n1   = n0 + 128;       // gate col of tile1 (g or o)

  for (int i = tid; i < BT * TT; i += 512)
    tokT[(i & (TT - 1)) * BT + (i >> 7)] = inst[b0 * TT + i];
  for (int i = tid; i < BT * HH; i += 512) hsh[i] = 0;
  for (int i = tid; i < 32 * 69; i += 512) Wr1_s[i] = Wr1[i];

  // weight fragments, B-operand layout: lane holds n, k = kt*32 + fg*8 + j
  bf16x8 wt[2][2][2];   // [tile][ktile][mat 0=ih 1=hh]
  float nb0, sb1;
#pragma unroll
  for (int tile = 0; tile < 2; tile++) {
    const int n = tile ? n1 : n0;
#pragma unroll
    for (int kt = 0; kt < 2; kt++) {
      const float* pa = Wih + n * 64 + kt * 32 + fg * 8;
      const float* pb = Whh + n * 64 + kt * 32 + fg * 8;
      bf16x8 fa, fb;
#pragma unroll
      for (int j = 0; j < 8; j++) { fa[j] = (short)f2bf(pa[j]); fb[j] = (short)f2bf(pb[j]); }
      wt[tile][kt][0] = fa; wt[tile][kt][1] = fb;
    }
  }
  nb0 = -L2E * (bih[n0] + bhh[n0]);                       // tile0 always sigmoid
  sb1 = (hi ? -L2E : L2E2) * (bih[n1] + bhh[n1]);         // g: tanh scale, o: sigmoid

  // x pipeline: Dx holds x-contribution for step t; xa holds x(t+1) fragments
  bf16x8 xa0, xa1;
  {
    const int tk = tokT[0 * BT + fr];
    const unsigned short* p = ebf + tk * 64 + fg * 8;
    xa0 = *(const bf16x8*)p; xa1 = *(const bf16x8*)(p + 32);
  }
  f32x4 Dx0 = {0.f,0.f,0.f,0.f}, Dx1 = {0.f,0.f,0.f,0.f};
  MFMA(Dx0, xa0, wt[0][0][0]); MFMA(Dx0, xa1, wt[0][1][0]);
  MFMA(Dx1, xa0, wt[1][0][0]); MFMA(Dx1, xa1, wt[1][1][0]);
  {
    const int tk = tokT[1 * BT + fr];
    const unsigned short* p = ebf + tk * 64 + fg * 8;
    xa0 = *(const bf16x8*)p; xa1 = *(const bf16x8*)(p + 32);
  }

  float cst[4] = {0.f,0.f,0.f,0.f};
  float pf[4], po[4];

  __syncthreads();

  for (int t = 0; t < TT; t++) {
    // ---- phase 1: h-MFMA + gate transcendentals ----
    const char* hb = (const char*)hsh + (t & 1) * (BT * HH * 2);
    const int sx = (fr & 7) << 4;
    bf16x8 ha0 = *(const bf16x8*)(hb + ((fr * 128 + fg * 16) ^ sx));
    bf16x8 ha1 = *(const bf16x8*)(hb + ((fr * 128 + 64 + fg * 16) ^ sx));

    f32x4 D0 = Dx0, D1 = Dx1;
    MFMA(D0, ha0, wt[0][0][1]); MFMA(D0, ha1, wt[0][1][1]);
    MFMA(D1, ha0, wt[1][0][1]); MFMA(D1, ha1, wt[1][1][1]);

    if (hi == 0) {
      // a = sigmoid(i) * tanh(g)
#pragma unroll
      for (int r = 0; r < 4; r++) {
        const int m = fg * 4 + r;
        const float gi = rcp_(1.f + exp2_(fmaf(D0[r], -L2E, nb0)));
        const float e  = exp2_(fmaf(D1[r], L2E2, sb1));
        const float tg = (e - 1.f) * rcp_(e + 1.f);
        a_s[m][jcol] = gi * tg;
      }
    } else {
#pragma unroll
      for (int r = 0; r < 4; r++) {
        pf[r] = rcp_(1.f + exp2_(fmaf(D0[r], -L2E, nb0)));
        po[r] = rcp_(1.f + exp2_(fmaf(D1[r], -L2E, sb1)));
      }
    }
    __syncthreads();   // a_s ready; h[t] fully consumed

    // ---- phase 2: next step's x-MFMA ∥ cell update ----
    if (t + 1 < TT) {
      f32x4 nx0 = {0.f,0.f,0.f,0.f}, nx1 = {0.f,0.f,0.f,0.f};
      MFMA(nx0, xa0, wt[0][0][0]); MFMA(nx0, xa1, wt[0][1][0]);
      MFMA(nx1, xa0, wt[1][0][0]); MFMA(nx1, xa1, wt[1][1][0]);
      Dx0 = nx0; Dx1 = nx1;
      if (t + 2 < TT) {
        const int tk = tokT[(t + 2) * BT + fr];
        const unsigned short* p = ebf + tk * 64 + fg * 8;
        xa0 = *(const bf16x8*)p; xa1 = *(const bf16x8*)(p + 32);
      }
    }
    if (hi == 1) {
      char* hwb = (char*)hsh + ((t + 1) & 1) * (BT * HH * 2);
#pragma unroll
      for (int r = 0; r < 4; r++) {
        const int m = fg * 4 + r;
        const float a = a_s[m][jcol];
        const float c = fmaf(pf[r], cst[r], a);
        cst[r] = c;
        const float e  = exp2_(L2E2 * fminf(c, 15.f));
        const float th = (e - 1.f) * rcp_(e + 1.f);
        const float hn = po[r] * th;
        *(unsigned short*)(hwb + ((m * 128 + 2 * jcol) ^ ((m & 7) << 4))) = f2bf(hn);
        if (t == TT - 1) a_s[m][jcol] = hn;   // publish fp32 h for the head
      }
    }
    __syncthreads();
  }

  // ---------- fused head: 32 lanes per batch row ----------
  const int m  = (w << 1) + (lane >> 5);   // 0..15
  const int o  = lane & 31;
  const int gb = b0 + m;

  // act_tag
  int key = -1;
#pragma unroll
  for (int q = 0; q < 4; q++) {
    const int t = o + q * 32;
    const int tk = tokT[t * BT + m];
    if (tk >= 1) key = max(key, (t << 16) | tk);
  }
#pragma unroll
  for (int s = 16; s; s >>= 1) key = max(key, __shfl_xor(key, s, 32));
  const float tag = (key >= 0 && (key & 0xFFFF) == 9) ? 1.f : 0.f;

  // hid base over h + tag
  float base = br1[o] + Wr1_s[o * 69 + 64] * tag;
  for (int f = 0; f < 64; f++) base += Wr1_s[o * 69 + f] * a_s[m][f];
  const float wr2o = Wr2[o];
  const float* cv = canvas + (size_t)gb * 100;

  float sc[25];
  float mx = -1e30f;
#pragma unroll
  for (int n = 0; n < 25; n++) {
    float acc = base;
#pragma unroll
    for (int d = 0; d < 4; d++) acc += Wr1_s[o * 69 + 65 + d] * cv[n * 4 + d];
    float p = wr2o * fmaxf(acc, 0.f);
#pragma unroll
    for (int s = 16; s; s >>= 1) p += __shfl_xor(p, s, 32);
    sc[n] = p + br2[0];
    mx = fmaxf(mx, sc[n]);
  }
  float sum = 0.f, rp2 = 0.f, rp3 = 0.f;
#pragma unroll
  for (int n = 0; n < 25; n++) {
    const float e = __expf(sc[n] - mx);
    sum += e;
    rp2 += e * cv[n * 4 + 2];
    rp3 += e * cv[n * 4 + 3];
  }
  const float inv = 1.f / sum;

  const float h0 = a_s[m][o], h1 = a_s[m][o + 32];
  float c0 = red32(h0 * Wc[o]       + h1 * Wc[32 + o]) + bc[0];
  float c1 = red32(h0 * Wc[64 + o]  + h1 * Wc[96 + o]) + bc[1];
  float c2 = red32(h0 * Wc[128 + o] + h1 * Wc[160 + o]) + bc[2];
  float s0 = red32(h0 * Ws[o]       + h1 * Ws[32 + o]) + bs[0];
  float s1 = red32(h0 * Ws[64 + o]  + h1 * Ws[96 + o]) + bs[1];
  float s2 = red32(h0 * Ws[128 + o] + h1 * Ws[160 + o]) + bs[2];
  float o0 = red32(h0 * Wo[o]       + h1 * Wo[32 + o]) + bo[0];
  float o1 = red32(h0 * Wo[64 + o]  + h1 * Wo[96 + o]) + bo[1];
  o0 = fminf(fmaxf(o0, -1.f), 1.f);
  o1 = fminf(fmaxf(o1, -1.f), 1.f);

  const float cm = fmaxf(c0, fmaxf(c1, c2));
  const float cl = cm + __logf(__expf(c0 - cm) + __expf(c1 - cm) + __expf(c2 - cm));
  const float sm = fmaxf(s0, fmaxf(s1, s2));
  const float sl = sm + __logf(__expf(s0 - sm) + __expf(s1 - sm) + __expf(s2 - sm));

  if (o == 0) {
    out[gb * 3 + 0] = c0 - cl; out[gb * 3 + 1] = c1 - cl; out[gb * 3 + 2] = c2 - cl;
    float* shp = out + (size_t)3 * B;
    shp[gb * 3 + 0] = s0 - sl; shp[gb * 3 + 1] = s1 - sl; shp[gb * 3 + 2] = s2 - sl;
    out[(size_t)6 * B + gb] = rp2 * inv + o0;
    out[(size_t)7 * B + gb] = rp3 * inv + o1;
  }
}

extern "C" void kernel_launch(void* const* d_in, const int* in_sizes, int n_in,
                              void* d_out, int out_size, void* d_ws, size_t ws_size,
                              hipStream_t stream) {
  const int*   inst   = (const int*)  d_in[0];
  const float* canvas = (const float*)d_in[1];
  const float* embed  = (const float*)d_in[4];
  const float* Wih    = (const float*)d_in[5];
  const float* Whh    = (const float*)d_in[6];
  const float* bih    = (const float*)d_in[7];
  const float* bhh    = (const float*)d_in[8];
  const float* Wc     = (const float*)d_in[9];
  const float* bc     = (const float*)d_in[10];
  const float* Ws_    = (const float*)d_in[11];
  const float* bs     = (const float*)d_in[12];
  const float* Wo     = (const float*)d_in[13];
  const float* bo     = (const float*)d_in[14];
  const float* Wr1    = (const float*)d_in[15];
  const float* br1    = (const float*)d_in[16];
  const float* Wr2    = (const float*)d_in[17];
  const float* br2    = (const float*)d_in[18];

  const int B  = in_sizes[0] / TT;       // 4096
  const int NE = in_sizes[4];            // 32001 * 64

  unsigned short* ebf = (unsigned short*)d_ws;

  convert_embed<<<(NE / 4 + 255) / 256, 256, 0, stream>>>(embed, ebf, NE);
  lstm_k<<<B / BT, 512, 0, stream>>>(inst, ebf, Wih, Whh, bih, bhh,
                                     canvas, Wc, bc, Ws_, bs, Wo, bo,
                                     Wr1, br1, Wr2, br2, (float*)d_out, B);
}

// Round 3
// 107.653 us; speedup vs baseline: 1.0474x; 1.0474x over previous
//
#include <hip/hip_runtime.h>
#include <hip/hip_bf16.h>

#define HH 64
#define TT 128
#define BT 8   // batch rows per block; MFMA M=16 rows 8-15 are duplicates of 0-7

typedef __attribute__((ext_vector_type(8))) short bf16x8;
typedef __attribute__((ext_vector_type(4))) float f32x4;

__device__ __forceinline__ unsigned short f2bf(float f) {
  union { float f; unsigned u; } v; v.f = f;
  return (unsigned short)((v.u + 0x7FFFu + ((v.u >> 16) & 1u)) >> 16);
}
__device__ __forceinline__ float rcp_(float x) { return __builtin_amdgcn_rcpf(x); }
__device__ __forceinline__ float exp2_(float x) { return __builtin_amdgcn_exp2f(x); }

#define L2E 1.44269504f
#define L2E2 2.88539008f

__device__ __forceinline__ float red32(float v) {
#pragma unroll
  for (int s = 16; s; s >>= 1) v += __shfl_xor(v, s, 32);
  return v;
}

// ---------- kernel 1: embed fp32 -> bf16 ----------
__global__ void convert_embed(const float* __restrict__ src,
                              unsigned short* __restrict__ dst, int n) {
  int base = (blockIdx.x * 256 + threadIdx.x) * 4;
  if (base + 4 <= n) {
    float4 v = *(const float4*)(src + base);
    ushort4 r;
    r.x = f2bf(v.x); r.y = f2bf(v.y); r.z = f2bf(v.z); r.w = f2bf(v.w);
    *(ushort4*)(dst + base) = r;
  } else {
    for (int k = base; k < n; k++) dst[k] = f2bf(src[k]);
  }
}

#define MFMA(acc, a, b) acc = __builtin_amdgcn_mfma_f32_16x16x32_bf16(a, b, acc, 0, 0, 0)

// ---------- kernel 2: fused LSTM + head, BT=8, 2 blocks/CU ----------
__global__ __launch_bounds__(256, 2) void lstm_k(
    const int* __restrict__ inst, const unsigned short* __restrict__ ebf,
    const float* __restrict__ Wih, const float* __restrict__ Whh,
    const float* __restrict__ bih, const float* __restrict__ bhh,
    const float* __restrict__ canvas,
    const float* __restrict__ Wc, const float* __restrict__ bc,
    const float* __restrict__ Ws, const float* __restrict__ bs,
    const float* __restrict__ Wo, const float* __restrict__ bo,
    const float* __restrict__ Wr1, const float* __restrict__ br1,
    const float* __restrict__ Wr2, const float* __restrict__ br2,
    float* __restrict__ out, int B)
{
  __shared__ int tokT[TT * BT];                 // [t][b_local]
  __shared__ unsigned short hsh[2 * BT * HH];   // 2 ping-pong buffers, bf16, swizzled
  __shared__ float h_s[BT][HH + 2];             // final h, fp32, for head
  __shared__ float Wr1_s[32 * 69];
  __shared__ float cv_s[BT * 100];

  const int tid  = threadIdx.x;
  const int lane = tid & 63;
  const int w    = tid >> 6;       // wave 0..3, owns gate-col tiles {w, w+4, w+8, w+12}
  const int fr   = lane & 15;
  const int fg   = lane >> 4;
  const int b0   = blockIdx.x * BT;
  const int jcol = w * 16 + fr;    // hidden column this lane touches
  const int hi2  = fg >> 1;        // which D-reg pair this lane finalizes
  const int row0 = (fg & 1) * 4 + hi2 * 2;   // first of the 2 cell rows this lane owns

  for (int i = tid; i < BT * TT; i += 256) {
    const int b = i >> 7, t = i & (TT - 1);
    tokT[t * BT + b] = inst[(size_t)(b0 + b) * TT + t];
  }
  for (int i = tid; i < 2 * BT * HH; i += 256) hsh[i] = 0;
  for (int i = tid; i < 32 * 69; i += 256) Wr1_s[i] = Wr1[i];
  for (int i = tid; i < BT * 100; i += 256) cv_s[i] = canvas[(size_t)b0 * 100 + i];

  // weight fragments (B-operand): lane holds col n, k = kt*32 + fg*8 + j
  bf16x8 wt[4][2][2];   // [gate q][ktile][0=ih 1=hh]
#pragma unroll
  for (int q = 0; q < 4; q++) {
    const int n = (w + q * 4) * 16 + fr;
#pragma unroll
    for (int kt = 0; kt < 2; kt++) {
      const float* pa = Wih + n * 64 + kt * 32 + fg * 8;
      const float* pb = Whh + n * 64 + kt * 32 + fg * 8;
      bf16x8 fa, fb;
#pragma unroll
      for (int j = 0; j < 8; j++) { fa[j] = (short)f2bf(pa[j]); fb[j] = (short)f2bf(pb[j]); }
      wt[q][kt][0] = fa; wt[q][kt][1] = fb;
    }
  }
  // biases (per gate, at this lane's column), pre-scaled for exp2
  const float nbi = -L2E  * (bih[jcol]       + bhh[jcol]);
  const float nbf = -L2E  * (bih[64 + jcol]  + bhh[64 + jcol]);
  const float sbg =  L2E2 * (bih[128 + jcol] + bhh[128 + jcol]);
  const float nbo = -L2E  * (bih[192 + jcol] + bhh[192 + jcol]);

  // loop-invariant LDS byte offsets (read: dup rows via fr&7; write: owned rows)
  const int rr7 = fr & 7;
  const int ra  = (rr7 * 128 + fg * 16) ^ (rr7 << 4);
  const int rb  = (rr7 * 128 + 64 + fg * 16) ^ (rr7 << 4);
  const int wa0 = (row0 * 128 + 2 * jcol) ^ ((row0 & 7) << 4);
  const int wa1 = ((row0 + 1) * 128 + 2 * jcol) ^ (((row0 + 1) & 7) << 4);
  char* const hs0 = (char*)hsh;
  char* const hs1 = hs0 + BT * HH * 2;

  __syncthreads();   // tokT/hsh ready before first prefetch

  bf16x8 xa0, xa1;
  {
    const int tk = tokT[0 * BT + rr7];
    const unsigned short* p = ebf + tk * 64 + fg * 8;
    xa0 = *(const bf16x8*)p; xa1 = *(const bf16x8*)(p + 32);
  }
  float cst0 = 0.f, cst1 = 0.f, hk0 = 0.f, hk1 = 0.f;

#define LSTM_STEP(RD, WR, T)                                                   \
  {                                                                            \
    bf16x8 ha0 = *(const bf16x8*)(RD + ra);                                    \
    bf16x8 ha1 = *(const bf16x8*)(RD + rb);                                    \
    const int tn = ((T) + 1 < TT) ? (T) + 1 : TT - 1;                          \
    const int tk = tokT[tn * BT + rr7];                                        \
    const unsigned short* px = ebf + tk * 64 + fg * 8;                         \
    bf16x8 xn0 = *(const bf16x8*)px;                                           \
    bf16x8 xn1 = *(const bf16x8*)(px + 32);                                    \
    f32x4 D0 = {0.f,0.f,0.f,0.f}, D1 = {0.f,0.f,0.f,0.f},                      \
          D2 = {0.f,0.f,0.f,0.f}, D3 = {0.f,0.f,0.f,0.f};                      \
    MFMA(D0, xa0, wt[0][0][0]); MFMA(D0, xa1, wt[0][1][0]);                    \
    MFMA(D1, xa0, wt[1][0][0]); MFMA(D1, xa1, wt[1][1][0]);                    \
    MFMA(D2, xa0, wt[2][0][0]); MFMA(D2, xa1, wt[2][1][0]);                    \
    MFMA(D3, xa0, wt[3][0][0]); MFMA(D3, xa1, wt[3][1][0]);                    \
    MFMA(D0, ha0, wt[0][0][1]); MFMA(D0, ha1, wt[0][1][1]);                    \
    MFMA(D1, ha0, wt[1][0][1]); MFMA(D1, ha1, wt[1][1][1]);                    \
    MFMA(D2, ha0, wt[2][0][1]); MFMA(D2, ha1, wt[2][1][1]);                    \
    MFMA(D3, ha0, wt[3][0][1]); MFMA(D3, ha1, wt[3][1][1]);                    \
    {                                                                          \
      const float i_ = hi2 ? D0[2] : D0[0];                                    \
      const float f_ = hi2 ? D1[2] : D1[0];                                    \
      const float g_ = hi2 ? D2[2] : D2[0];                                    \
      const float o_ = hi2 ? D3[2] : D3[0];                                    \
      const float gi = rcp_(1.f + exp2_(fmaf(i_, -L2E, nbi)));                 \
      const float gf = rcp_(1.f + exp2_(fmaf(f_, -L2E, nbf)));                 \
      const float eg = exp2_(fminf(fmaf(g_, L2E2, sbg), 60.f));                \
      const float tg = (eg - 1.f) * rcp_(eg + 1.f);                            \
      const float go = rcp_(1.f + exp2_(fmaf(o_, -L2E, nbo)));                 \
      const float c  = fmaf(gf, cst0, gi * tg);                                \
      cst0 = c;                                                                \
      const float ec = exp2_(L2E2 * fminf(c, 8.f));                            \
      const float th = (ec - 1.f) * rcp_(ec + 1.f);                            \
      hk0 = go * th;                                                           \
      union { float f; unsigned u; } cv; cv.f = hk0;                           \
      *(unsigned short*)(WR + wa0) = (unsigned short)((cv.u + 0x8000u) >> 16); \
    }                                                                          \
    {                                                                          \
      const float i_ = hi2 ? D0[3] : D0[1];                                    \
      const float f_ = hi2 ? D1[3] : D1[1];                                    \
      const float g_ = hi2 ? D2[3] : D2[1];                                    \
      const float o_ = hi2 ? D3[3] : D3[1];                                    \
      const float gi = rcp_(1.f + exp2_(fmaf(i_, -L2E, nbi)));                 \
      const float gf = rcp_(1.f + exp2_(fmaf(f_, -L2E, nbf)));                 \
      const float eg = exp2_(fminf(fmaf(g_, L2E2, sbg), 60.f));                \
      const float tg = (eg - 1.f) * rcp_(eg + 1.f);                            \
      const float go = rcp_(1.f + exp2_(fmaf(o_, -L2E, nbo)));                 \
      const float c  = fmaf(gf, cst1, gi * tg);                                \
      cst1 = c;                                                                \
      const float ec = exp2_(L2E2 * fminf(c, 8.f));                            \
      const float th = (ec - 1.f) * rcp_(ec + 1.f);                            \
      hk1 = go * th;                                                           \
      union { float f; unsigned u; } cv; cv.f = hk1;                           \
      *(unsigned short*)(WR + wa1) = (unsigned short)((cv.u + 0x8000u) >> 16); \
    }                                                                          \
    __syncthreads();                                                           \
    xa0 = xn0; xa1 = xn1;                                                      \
  }

  for (int t = 0; t < TT; t += 2) {
    LSTM_STEP(hs0, hs1, t);
    LSTM_STEP(hs1, hs0, t + 1);
  }
#undef LSTM_STEP

  h_s[row0][jcol]     = hk0;
  h_s[row0 + 1][jcol] = hk1;
  __syncthreads();

  // ---------- fused head: 32 lanes per batch row (8 rows/block) ----------
  const int m  = tid >> 5;       // 0..7
  const int o  = tid & 31;
  const int gb = b0 + m;

  // act_tag
  int key = -1;
#pragma unroll
  for (int q = 0; q < 4; q++) {
    const int t = o + q * 32;
    const int tk = tokT[t * BT + m];
    if (tk >= 1) key = max(key, (t << 16) | tk);
  }
#pragma unroll
  for (int s = 16; s; s >>= 1) key = max(key, __shfl_xor(key, s, 32));
  const float tag = (key >= 0 && (key & 0xFFFF) == 9) ? 1.f : 0.f;

  float base = br1[o] + Wr1_s[o * 69 + 64] * tag;
  for (int f = 0; f < 64; f++) base += Wr1_s[o * 69 + f] * h_s[m][f];
  const float wr2o = Wr2[o];
  const float* cv = cv_s + m * 100;

  float sc[25];
  float mx = -1e30f;
#pragma unroll
  for (int n = 0; n < 25; n++) {
    float acc = base;
#pragma unroll
    for (int d = 0; d < 4; d++) acc += Wr1_s[o * 69 + 65 + d] * cv[n * 4 + d];
    float p = wr2o * fmaxf(acc, 0.f);
#pragma unroll
    for (int s = 16; s; s >>= 1) p += __shfl_xor(p, s, 32);
    sc[n] = p + br2[0];
    mx = fmaxf(mx, sc[n]);
  }
  float sum = 0.f, rp2 = 0.f, rp3 = 0.f;
#pragma unroll
  for (int n = 0; n < 25; n++) {
    const float e = __expf(sc[n] - mx);
    sum += e;
    rp2 += e * cv[n * 4 + 2];
    rp3 += e * cv[n * 4 + 3];
  }
  const float inv = 1.f / sum;

  const float h0 = h_s[m][o], h1 = h_s[m][o + 32];
  float c0 = red32(h0 * Wc[o]       + h1 * Wc[32 + o])  + bc[0];
  float c1 = red32(h0 * Wc[64 + o]  + h1 * Wc[96 + o])  + bc[1];
  float c2 = red32(h0 * Wc[128 + o] + h1 * Wc[160 + o]) + bc[2];
  float s0 = red32(h0 * Ws[o]       + h1 * Ws[32 + o])  + bs[0];
  float s1 = red32(h0 * Ws[64 + o]  + h1 * Ws[96 + o])  + bs[1];
  float s2 = red32(h0 * Ws[128 + o] + h1 * Ws[160 + o]) + bs[2];
  float o0 = red32(h0 * Wo[o]       + h1 * Wo[32 + o])  + bo[0];
  float o1 = red32(h0 * Wo[64 + o]  + h1 * Wo[96 + o])  + bo[1];
  o0 = fminf(fmaxf(o0, -1.f), 1.f);
  o1 = fminf(fmaxf(o1, -1.f), 1.f);

  const float cm = fmaxf(c0, fmaxf(c1, c2));
  const float cl = cm + __logf(__expf(c0 - cm) + __expf(c1 - cm) + __expf(c2 - cm));
  const float sm = fmaxf(s0, fmaxf(s1, s2));
  const float sl = sm + __logf(__expf(s0 - sm) + __expf(s1 - sm) + __expf(s2 - sm));

  if (o == 0) {
    out[gb * 3 + 0] = c0 - cl; out[gb * 3 + 1] = c1 - cl; out[gb * 3 + 2] = c2 - cl;
    float* shp = out + (size_t)3 * B;
    shp[gb * 3 + 0] = s0 - sl; shp[gb * 3 + 1] = s1 - sl; shp[gb * 3 + 2] = s2 - sl;
    out[(size_t)6 * B + gb] = rp2 * inv + o0;
    out[(size_t)7 * B + gb] = rp3 * inv + o1;
  }
}

extern "C" void kernel_launch(void* const* d_in, const int* in_sizes, int n_in,
                              void* d_out, int out_size, void* d_ws, size_t ws_size,
                              hipStream_t stream) {
  const int*   inst   = (const int*)  d_in[0];
  const float* canvas = (const float*)d_in[1];
  const float* embed  = (const float*)d_in[4];
  const float* Wih    = (const float*)d_in[5];
  const float* Whh    = (const float*)d_in[6];
  const float* bih    = (const float*)d_in[7];
  const float* bhh    = (const float*)d_in[8];
  const float* Wc     = (const float*)d_in[9];
  const float* bc     = (const float*)d_in[10];
  const float* Ws_    = (const float*)d_in[11];
  const float* bs     = (const float*)d_in[12];
  const float* Wo     = (const float*)d_in[13];
  const float* bo     = (const float*)d_in[14];
  const float* Wr1    = (const float*)d_in[15];
  const float* br1    = (const float*)d_in[16];
  const float* Wr2    = (const float*)d_in[17];
  const float* br2    = (const float*)d_in[18];

  const int B  = in_sizes[0] / TT;       // 4096
  const int NE = in_sizes[4];            // 32001 * 64

  unsigned short* ebf = (unsigned short*)d_ws;

  convert_embed<<<(NE / 4 + 255) / 256, 256, 0, stream>>>(embed, ebf, NE);
  lstm_k<<<B / BT, 256, 0, stream>>>(inst, ebf, Wih, Whh, bih, bhh,
                                     canvas, Wc, bc, Ws_, bs, Wo, bo,
                                     Wr1, br1, Wr2, br2, (float*)d_out, B);
}

// Round 4
// 98.659 us; speedup vs baseline: 1.1429x; 1.0912x over previous
//
#include <hip/hip_runtime.h>
#include <hip/hip_bf16.h>

#define HH 64
#define TT 128
#define TP 132   // padded token row stride (ints) to break bank alignment
#define BT 16

typedef __attribute__((ext_vector_type(8))) short bf16x8;
typedef __attribute__((ext_vector_type(4))) float f32x4;

__device__ __forceinline__ unsigned short f2bf(float f) {
  union { float f; unsigned u; } v; v.f = f;
  return (unsigned short)((v.u + 0x8000u) >> 16);
}
__device__ __forceinline__ float rcp_(float x) { return __builtin_amdgcn_rcpf(x); }
__device__ __forceinline__ float exp2_(float x) { return __builtin_amdgcn_exp2f(x); }

#define L2E 1.44269504f
#define L2E2 2.88539008f

__device__ __forceinline__ float red32(float v) {
#pragma unroll
  for (int s = 16; s; s >>= 1) v += __shfl_xor(v, s, 32);
  return v;
}

// ---------- kernel 1: embed fp32 -> bf16 ----------
__global__ void convert_embed(const float* __restrict__ src,
                              unsigned short* __restrict__ dst, int n) {
  int base = (blockIdx.x * 256 + threadIdx.x) * 4;
  if (base + 4 <= n) {
    float4 v = *(const float4*)(src + base);
    ushort4 r;
    r.x = f2bf(v.x); r.y = f2bf(v.y); r.z = f2bf(v.z); r.w = f2bf(v.w);
    *(ushort4*)(dst + base) = r;
  } else {
    for (int k = base; k < n; k++) dst[k] = f2bf(src[k]);
  }
}

#define MFMA(acc, a, b) acc = __builtin_amdgcn_mfma_f32_16x16x32_bf16(a, b, acc, 0, 0, 0)

// ---------- kernel 2: fused LSTM + head, BT=16, 1 block/CU ----------
__global__ __launch_bounds__(256, 1) void lstm_k(
    const int* __restrict__ inst, const unsigned short* __restrict__ ebf,
    const float* __restrict__ Wih, const float* __restrict__ Whh,
    const float* __restrict__ bih, const float* __restrict__ bhh,
    const float* __restrict__ canvas,
    const float* __restrict__ Wc, const float* __restrict__ bc,
    const float* __restrict__ Ws, const float* __restrict__ bs,
    const float* __restrict__ Wo, const float* __restrict__ bo,
    const float* __restrict__ Wr1, const float* __restrict__ br1,
    const float* __restrict__ Wr2, const float* __restrict__ br2,
    float* __restrict__ out, int B)
{
  __shared__ int tokT[BT * TP];                 // [b_local][t], padded rows
  __shared__ unsigned short hsh[2 * BT * HH];   // ping-pong h, bf16, XOR-swizzled
  __shared__ float h_s[BT][68];                 // final h fp32 for head
  __shared__ float Wr1_s[32 * 69];
  __shared__ float cv_s[BT * 100];

  const int tid  = threadIdx.x;
  const int lane = tid & 63;
  const int w    = tid >> 6;       // wave 0..3, gate tiles {w, w+4, w+8, w+12}
  const int fr   = lane & 15;
  const int fg   = lane >> 4;
  const int b0   = blockIdx.x * BT;
  const int jcol = w * 16 + fr;    // hidden column this lane produces

  for (int i = tid; i < BT * TT; i += 256) {
    const int b = i >> 7, t = i & (TT - 1);
    tokT[b * TP + t] = inst[(size_t)(b0 + b) * TT + t];
  }
  for (int i = tid; i < BT * HH; i += 256) hsh[i] = 0;   // buffer0 = h(0) = 0
  for (int i = tid; i < 32 * 69; i += 256) Wr1_s[i] = Wr1[i];
  for (int i = tid; i < BT * 100; i += 256) cv_s[i] = canvas[(size_t)b0 * 100 + i];

  // weight fragments (B-operand): lane holds col n, k = kt*32 + fg*8 + j
  bf16x8 wt[4][2][2];   // [gate q][ktile][0=ih 1=hh]
#pragma unroll
  for (int q = 0; q < 4; q++) {
    const int n = (w + q * 4) * 16 + fr;
#pragma unroll
    for (int kt = 0; kt < 2; kt++) {
      const float* pa = Wih + n * 64 + kt * 32 + fg * 8;
      const float* pb = Whh + n * 64 + kt * 32 + fg * 8;
      bf16x8 fa, fb;
#pragma unroll
      for (int j = 0; j < 8; j++) {
        union { float f; unsigned u; } va, vb; va.f = pa[j]; vb.f = pb[j];
        fa[j] = (short)((va.u + 0x8000u) >> 16);
        fb[j] = (short)((vb.u + 0x8000u) >> 16);
      }
      wt[q][kt][0] = fa; wt[q][kt][1] = fb;
    }
  }
  // pre-scaled biases for exp2 forms
  const float nbi = -L2E  * (bih[jcol]       + bhh[jcol]);
  const float nbf = -L2E  * (bih[64 + jcol]  + bhh[64 + jcol]);
  const float sbg =  L2E2 * (bih[128 + jcol] + bhh[128 + jcol]);
  const float nbo = -L2E  * (bih[192 + jcol] + bhh[192 + jcol]);

  // loop-invariant LDS byte offsets
  const int sx = (fr & 7) << 4;
  const int ra = (fr * 128 + fg * 16) ^ sx;
  const int rb = (fr * 128 + 64 + fg * 16) ^ sx;
  int wa[4];
#pragma unroll
  for (int r = 0; r < 4; r++) {
    const int m = fg * 4 + r;
    wa[r] = (m * 128 + 2 * jcol) ^ ((m & 7) << 4);
  }
  char* const hs0 = (char*)hsh;
  char* const hs1 = hs0 + BT * HH * 2;
  const int* const tokrow = tokT + fr * TP;

  __syncthreads();   // staging complete

  bf16x8 xa0, xa1;
  {
    const int tk = tokrow[0];
    const unsigned short* p = ebf + tk * 64 + fg * 8;
    xa0 = *(const bf16x8*)p; xa1 = *(const bf16x8*)(p + 32);
  }
  float cst[4] = {0.f, 0.f, 0.f, 0.f};
  float hk[4];
  const f32x4 z4 = {0.f, 0.f, 0.f, 0.f};

#define LSTM_STEP(RD, WR, T)                                                   \
  {                                                                            \
    const int tknext = tokrow[((T) + 1) & (TT - 1)];                           \
    bf16x8 ha0 = *(const bf16x8*)((RD) + ra);                                  \
    bf16x8 ha1 = *(const bf16x8*)((RD) + rb);                                  \
    f32x4 D0 = z4, D1 = z4, D2 = z4, D3 = z4;                                  \
    MFMA(D0, xa0, wt[0][0][0]); MFMA(D0, xa1, wt[0][1][0]);                    \
    MFMA(D1, xa0, wt[1][0][0]); MFMA(D1, xa1, wt[1][1][0]);                    \
    MFMA(D2, xa0, wt[2][0][0]); MFMA(D2, xa1, wt[2][1][0]);                    \
    MFMA(D3, xa0, wt[3][0][0]); MFMA(D3, xa1, wt[3][1][0]);                    \
    const unsigned short* px = ebf + tknext * 64 + fg * 8;                     \
    bf16x8 xn0 = *(const bf16x8*)px;                                           \
    bf16x8 xn1 = *(const bf16x8*)(px + 32);                                    \
    MFMA(D0, ha0, wt[0][0][1]); MFMA(D0, ha1, wt[0][1][1]);                    \
    MFMA(D1, ha0, wt[1][0][1]); MFMA(D1, ha1, wt[1][1][1]);                    \
    MFMA(D2, ha0, wt[2][0][1]); MFMA(D2, ha1, wt[2][1][1]);                    \
    MFMA(D3, ha0, wt[3][0][1]); MFMA(D3, ha1, wt[3][1][1]);                    \
    _Pragma("unroll")                                                          \
    for (int r = 0; r < 4; r++) {                                              \
      const float pi = exp2_(fmaf(D0[r], -L2E, nbi));    /* e^-i  */           \
      const float pf = exp2_(fmaf(D1[r], -L2E, nbf));    /* e^-f  */           \
      const float eg = exp2_(fmaf(D2[r], L2E2, sbg));    /* e^2g  */           \
      const float po = exp2_(fmaf(D3[r], -L2E, nbo));    /* e^-o  */           \
      const float a  = (eg - 1.f) * rcp_((1.f + pi) * (eg + 1.f));             \
      const float c  = fmaf(rcp_(1.f + pf), cst[r], a);                        \
      cst[r] = c;                                                              \
      const float ec = exp2_(fminf(L2E2 * c, 60.f));     /* e^2c  */           \
      const float hn = (ec - 1.f) * rcp_((1.f + po) * (ec + 1.f));             \
      hk[r] = hn;                                                              \
      union { float f; unsigned u; } cv; cv.f = hn;                            \
      *(unsigned short*)((WR) + wa[r]) = (unsigned short)((cv.u + 0x8000u) >> 16); \
    }                                                                          \
    __syncthreads();                                                           \
    xa0 = xn0; xa1 = xn1;                                                      \
  }

  for (int t = 0; t < TT; t += 2) {
    LSTM_STEP(hs0, hs1, t);
    LSTM_STEP(hs1, hs0, t + 1);
  }
#undef LSTM_STEP

#pragma unroll
  for (int r = 0; r < 4; r++) h_s[fg * 4 + r][jcol] = hk[r];
  __syncthreads();

  // ---------- fused head: 32 lanes per row, 2 passes of 8 rows ----------
  for (int p = 0; p < 2; p++) {
    const int m  = p * 8 + (tid >> 5);
    const int o  = tid & 31;
    const int gb = b0 + m;

    // act_tag
    int key = -1;
#pragma unroll
    for (int q = 0; q < 4; q++) {
      const int t = o + q * 32;
      const int tk = tokT[m * TP + t];
      if (tk >= 1) key = max(key, (t << 16) | tk);
    }
#pragma unroll
    for (int s = 16; s; s >>= 1) key = max(key, __shfl_xor(key, s, 32));
    const float tag = (key >= 0 && (key & 0xFFFF) == 9) ? 1.f : 0.f;

    float base = br1[o] + Wr1_s[o * 69 + 64] * tag;
    for (int f = 0; f < 64; f++) base += Wr1_s[o * 69 + f] * h_s[m][f];
    const float wr2o = Wr2[o];
    const float* cv = cv_s + m * 100;

    float sc[25];
    float mx = -1e30f;
#pragma unroll
    for (int n = 0; n < 25; n++) {
      float acc = base;
#pragma unroll
      for (int d = 0; d < 4; d++) acc += Wr1_s[o * 69 + 65 + d] * cv[n * 4 + d];
      float pp = wr2o * fmaxf(acc, 0.f);
#pragma unroll
      for (int s = 16; s; s >>= 1) pp += __shfl_xor(pp, s, 32);
      sc[n] = pp + br2[0];
      mx = fmaxf(mx, sc[n]);
    }
    float sum = 0.f, rp2 = 0.f, rp3 = 0.f;
#pragma unroll
    for (int n = 0; n < 25; n++) {
      const float e = __expf(sc[n] - mx);
      sum += e;
      rp2 += e * cv[n * 4 + 2];
      rp3 += e * cv[n * 4 + 3];
    }
    const float inv = 1.f / sum;

    const float h0 = h_s[m][o], h1 = h_s[m][o + 32];
    float c0 = red32(h0 * Wc[o]       + h1 * Wc[32 + o])  + bc[0];
    float c1 = red32(h0 * Wc[64 + o]  + h1 * Wc[96 + o])  + bc[1];
    float c2 = red32(h0 * Wc[128 + o] + h1 * Wc[160 + o]) + bc[2];
    float s0 = red32(h0 * Ws[o]       + h1 * Ws[32 + o])  + bs[0];
    float s1 = red32(h0 * Ws[64 + o]  + h1 * Ws[96 + o])  + bs[1];
    float s2 = red32(h0 * Ws[128 + o] + h1 * Ws[160 + o]) + bs[2];
    float o0 = red32(h0 * Wo[o]       + h1 * Wo[32 + o])  + bo[0];
    float o1 = red32(h0 * Wo[64 + o]  + h1 * Wo[96 + o])  + bo[1];
    o0 = fminf(fmaxf(o0, -1.f), 1.f);
    o1 = fminf(fmaxf(o1, -1.f), 1.f);

    const float cm = fmaxf(c0, fmaxf(c1, c2));
    const float cl = cm + __logf(__expf(c0 - cm) + __expf(c1 - cm) + __expf(c2 - cm));
    const float sm = fmaxf(s0, fmaxf(s1, s2));
    const float sl = sm + __logf(__expf(s0 - sm) + __expf(s1 - sm) + __expf(s2 - sm));

    if (o == 0) {
      out[gb * 3 + 0] = c0 - cl; out[gb * 3 + 1] = c1 - cl; out[gb * 3 + 2] = c2 - cl;
      float* shp = out + (size_t)3 * B;
      shp[gb * 3 + 0] = s0 - sl; shp[gb * 3 + 1] = s1 - sl; shp[gb * 3 + 2] = s2 - sl;
      out[(size_t)6 * B + gb] = rp2 * inv + o0;
      out[(size_t)7 * B + gb] = rp3 * inv + o1;
    }
  }
}

extern "C" void kernel_launch(void* const* d_in, const int* in_sizes, int n_in,
                              void* d_out, int out_size, void* d_ws, size_t ws_size,
                              hipStream_t stream) {
  const int*   inst   = (const int*)  d_in[0];
  const float* canvas = (const float*)d_in[1];
  const float* embed  = (const float*)d_in[4];
  const float* Wih    = (const float*)d_in[5];
  const float* Whh    = (const float*)d_in[6];
  const float* bih    = (const float*)d_in[7];
  const float* bhh    = (const float*)d_in[8];
  const float* Wc     = (const float*)d_in[9];
  const float* bc     = (const float*)d_in[10];
  const float* Ws_    = (const float*)d_in[11];
  const float* bs     = (const float*)d_in[12];
  const float* Wo     = (const float*)d_in[13];
  const float* bo     = (const float*)d_in[14];
  const float* Wr1    = (const float*)d_in[15];
  const float* br1    = (const float*)d_in[16];
  const float* Wr2    = (const float*)d_in[17];
  const float* br2    = (const float*)d_in[18];

  const int B  = in_sizes[0] / TT;       // 4096
  const int NE = in_sizes[4];            // 32001 * 64

  unsigned short* ebf = (unsigned short*)d_ws;

  convert_embed<<<(NE / 4 + 255) / 256, 256, 0, stream>>>(embed, ebf, NE);
  lstm_k<<<B / BT, 256, 0, stream>>>(inst, ebf, Wih, Whh, bih, bhh,
                                     canvas, Wc, bc, Ws_, bs, Wo, bo,
                                     Wr1, br1, Wr2, br2, (float*)d_out, B);
}